// Round 21
// baseline (88.715 us; speedup 1.0000x reference)
//
#include <hip/hip_runtime.h>

typedef __attribute__((ext_vector_type(8))) __bf16 bf16x8;
typedef __attribute__((ext_vector_type(4))) float f32x4;

__device__ __forceinline__ unsigned short f2bf(float f) {
    unsigned int u = __builtin_bit_cast(unsigned int, f);
    u = (u + 0x7FFFu + ((u >> 16) & 1u)) >> 16;
    return (unsigned short)u;
}

// ---- K0: repack weights (both fragment-major) + objective init.
//   Wt1fm: slice tap: [mtile 0..7][lane][8]  (o=mt*16+lrow, i=kgrp*8+j)
//   Wt2fm: slice s=kc*9+tap: [(ot*2+khalf)*64 + lane][8]
__global__ void __launch_bounds__(256) prep_w(const float* __restrict__ W1,
                                              const float* __restrict__ W2,
                                              const float* __restrict__ obj,
                                              unsigned short* __restrict__ Wt1,
                                              unsigned short* __restrict__ Wt2,
                                              float* __restrict__ out) {
    int tid = blockIdx.x * 256 + threadIdx.x;
    if (tid < 32) out[8388608 + tid] = obj[tid];    // objective init (pre-mega)
    if (tid < 36864) {                       // W1: [128][32][9] -> fragment-major
        int tt = tid % 9, rem = tid / 9;
        int i = rem & 31, o = rem >> 5;
        int mt = o >> 4, lr = o & 15, kg = i >> 3, j = i & 7;
        Wt1[(size_t)((tt * 8 + mt) * 64 + kg * 16 + lr) * 8 + j] = f2bf(W1[tid]);
    }
    if (tid < 110592) {                      // W2: [96][128][9] -> fragment-major
        int tt = tid % 9, rem = tid / 9;
        int i = rem & 127, o = rem >> 7;
        int kc = i >> 6, ii = i & 63;
        int khalf = ii >> 5, kgrp = (ii >> 3) & 3, j = ii & 7;
        int o_tile = o >> 4, lrow = o & 15;
        int s = kc * 9 + tt;
        Wt2[(size_t)s * 6144 +
            (size_t)(((o_tile * 2 + khalf) * 64 + kgrp * 16 + lrow) * 8 + j)] = f2bf(W2[tid]);
    }
}

// ---- MEGA: identity copy + x stage + conv1(->LDS, per-chunk) + conv2 + spline.
//      TH=2, 1024 blocks, 512 thr. hbuf eliminated.
__global__ void __launch_bounds__(512) mega(const float* __restrict__ x,
                                            const float* __restrict__ b1,
                                            const float* __restrict__ b2,
                                            const unsigned short* __restrict__ Wt1,
                                            const unsigned short* __restrict__ Wt2,
                                            float* __restrict__ out) {
    const int LWX = 40;                          // x tile: 32 ch + 8 pad
    const int LWA = 72;                          // h tile: 64 ch + 8 pad
    __shared__ __align__(16) unsigned short sx[6 * 66 * LWX];  // 31,680 B
    __shared__ __align__(16) unsigned short hb[4 * 66 * LWA];  // 38,016 B
    __shared__ float red[8];
    float* pm = reinterpret_cast<float*>(sx);    // params alias [64][101] f32 = 25,856 B

    int raw = blockIdx.x;                        // 1024 blocks
    int wg = (raw & 7) * 128 + (raw >> 3);       // XCD-contiguous swizzle (bijective)
    int b = wg >> 5, h0 = (wg & 31) << 1;        // TH = 2 output rows
    int t = threadIdx.x;
    int wid = t >> 6, lane = t & 63;
    int lrow = lane & 15, kgrp = lane >> 4;
    int mg = wid >> 2, ng = wid & 3;             // 2 Mgrp x 4 Ngrp (both convs)
    int mb2 = mg * 3;                            // conv2: 3 M-tiles (48 ch)

    // -- identity copy (rows h0, h0+1) --
#pragma unroll
    for (int j = 0; j < 2; ++j) {
        int idx = j * 512 + t;                   // 1024 float4 = 2 rows x 32 ch x 16 w4
        int c = idx >> 5, row = (idx >> 4) & 1, w4 = idx & 15;
        size_t off = (((size_t)b * 64 + c) * 64 + (h0 + row)) * 16 + w4;
        reinterpret_cast<float4*>(out)[off] = reinterpret_cast<const float4*>(x)[off];
    }

    // -- stage sx: x[b, 0:32, h0-2..h0+3, :] transposed; halo cols + rows zero --
    if (t < 48) {                                // zero halo cols 0 and 65
        int row = t >> 3, k = t & 7;
        int col = (k & 1) ? 65 : 0, c0 = (k >> 1) * 8;
        *reinterpret_cast<uint4*>(&sx[(row * 66 + col) * LWX + c0]) = uint4{0, 0, 0, 0};
    }
    {
        int w = t & 63, c4 = (t >> 6) * 4;       // each thread: 4 adjacent channels
        const float* xb = x + (size_t)b * 262144;
#pragma unroll
        for (int row = 0; row < 6; ++row) {
            int gh = h0 - 2 + row;
            unsigned short* srow = &sx[(row * 66 + w + 1) * LWX];
            if ((unsigned)gh < 64u) {
                const float* xr = xb + (size_t)gh * 64;
#pragma unroll
                for (int cc = 0; cc < 2; ++cc) {
                    int c = c4 + cc * 2;
                    unsigned pk = (unsigned)f2bf(xr[(size_t)c * 4096 + w]) |
                                  ((unsigned)f2bf(xr[(size_t)(c + 1) * 4096 + w]) << 16);
                    *reinterpret_cast<unsigned*>(&srow[c]) = pk;
                }
            } else {
                *reinterpret_cast<unsigned*>(&srow[c4]) = 0u;
                *reinterpret_cast<unsigned*>(&srow[c4 + 2]) = 0u;
            }
        }
    }
    if (t < 64) {                                // zero hb halo cols 0 and 65 (once)
        int row = t >> 4, k = t & 15;
        int col = (k & 1) ? 65 : 0, c0 = (k >> 1) * 8;
        *reinterpret_cast<uint4*>(&hb[(row * 66 + col) * LWA + c0]) = uint4{0, 0, 0, 0};
    }
    __syncthreads();                             // sx ready

    const unsigned short* wfb1 = Wt1 + (size_t)lane * 8;
    const unsigned short* wfb2 = Wt2 + (size_t)lane * 8;

    f32x4 acc2[3][2];
#pragma unroll
    for (int i = 0; i < 3; ++i)
#pragma unroll
        for (int j = 0; j < 2; ++j) acc2[i][j] = f32x4{0.f, 0.f, 0.f, 0.f};

    for (int kc2 = 0; kc2 < 2; ++kc2) {          // two 64-ch h chunks
        // ---- conv1 chunk: h rows h0-1..h0+2, out ch kc2*64..+63 -> hb ----
        f32x4 acc1[2][4];
#pragma unroll
        for (int i = 0; i < 2; ++i)
#pragma unroll
            for (int j = 0; j < 4; ++j) acc1[i][j] = f32x4{0.f, 0.f, 0.f, 0.f};
#pragma unroll
        for (int tap = 0; tap < 9; ++tap) {
            int dh = tap / 3, dw = tap % 3;
            bf16x8 wa[2];
#pragma unroll
            for (int mi = 0; mi < 2; ++mi) {
                int mt = kc2 * 4 + mg * 2 + mi;  // global mtile 0..7
                wa[mi] = *reinterpret_cast<const bf16x8*>(wfb1 + (size_t)(tap * 8 + mt) * 512);
            }
#pragma unroll
            for (int ni = 0; ni < 4; ++ni) {
                int nt = ng * 4 + ni;            // 0..15: hrow = nt>>2, wtile = nt&3
                int hrow = nt >> 2, wt2 = nt & 3;
                bf16x8 bx = *reinterpret_cast<const bf16x8*>(
                    &sx[((hrow + dh) * 66 + wt2 * 16 + lrow + dw) * LWX + kgrp * 8]);
#pragma unroll
                for (int mi = 0; mi < 2; ++mi)
                    acc1[mi][ni] = __builtin_amdgcn_mfma_f32_16x16x32_bf16(wa[mi], bx, acc1[mi][ni], 0, 0, 0);
            }
        }
        // write hb (+bias, ReLU; zero rows whose global h is out of range)
#pragma unroll
        for (int mi = 0; mi < 2; ++mi) {
            int chc = (mg * 2 + mi) * 16 + kgrp * 4;    // ch-in-chunk base
            int och = kc2 * 64 + chc;
            float bb0 = b1[och], bb1 = b1[och + 1], bb2 = b1[och + 2], bb3 = b1[och + 3];
#pragma unroll
            for (int ni = 0; ni < 4; ++ni) {
                int nt = ng * 4 + ni;
                int hrow = nt >> 2, wt2 = nt & 3;
                bool valid = (unsigned)(h0 - 1 + hrow) < 64u;
                f32x4 v = acc1[mi][ni];
                unsigned short r0 = valid ? f2bf(fmaxf(v[0] + bb0, 0.f)) : (unsigned short)0;
                unsigned short r1 = valid ? f2bf(fmaxf(v[1] + bb1, 0.f)) : (unsigned short)0;
                unsigned short r2 = valid ? f2bf(fmaxf(v[2] + bb2, 0.f)) : (unsigned short)0;
                unsigned short r3 = valid ? f2bf(fmaxf(v[3] + bb3, 0.f)) : (unsigned short)0;
                uint2 pk;
                pk.x = (unsigned)r0 | ((unsigned)r1 << 16);
                pk.y = (unsigned)r2 | ((unsigned)r3 << 16);
                *reinterpret_cast<uint2*>(
                    &hb[(hrow * 66 + wt2 * 16 + lrow + 1) * LWA + chc]) = pk;
            }
        }
        __syncthreads();                         // hb chunk ready

        // ---- conv2 taps for this chunk (reads hb; weights L2-direct) ----
#pragma unroll
        for (int tap = 0; tap < 9; ++tap) {
            int s = kc2 * 9 + tap;
            const unsigned short* wsl = wfb2 + (size_t)s * 6144;
            int dh = tap / 3, dw = tap % 3;
            bf16x8 wfr[3][2];
#pragma unroll
            for (int mi = 0; mi < 3; ++mi) {
                int ot = mb2 + mi;
                wfr[mi][0] = *reinterpret_cast<const bf16x8*>(wsl + (size_t)(ot * 2 + 0) * 512);
                wfr[mi][1] = *reinterpret_cast<const bf16x8*>(wsl + (size_t)(ot * 2 + 1) * 512);
            }
#pragma unroll
            for (int ni = 0; ni < 2; ++ni) {
                int nt = ng * 2 + ni;            // 0..7
                int rr = nt >> 2, wcol = (nt & 3) * 16 + lrow;
                int base = ((rr + dh) * 66 + wcol + dw) * LWA;
                bf16x8 a0 = *reinterpret_cast<const bf16x8*>(&hb[base + kgrp * 8]);
                bf16x8 a1 = *reinterpret_cast<const bf16x8*>(&hb[base + 32 + kgrp * 8]);
#pragma unroll
                for (int mi = 0; mi < 3; ++mi) {
                    acc2[mi][ni] = __builtin_amdgcn_mfma_f32_16x16x32_bf16(wfr[mi][0], a0, acc2[mi][ni], 0, 0, 0);
                    acc2[mi][ni] = __builtin_amdgcn_mfma_f32_16x16x32_bf16(wfr[mi][1], a1, acc2[mi][ni], 0, 0, 0);
                }
            }
        }
        __syncthreads();                         // hb reads done (free for next chunk)
    }

    // ---- epilogue: two 64-position halves (rows h0/h0+1), params over sx ----
    float lad_acc = 0.f;
    for (int half = 0; half < 2; ++half) {
        if (half) __syncthreads();               // prev-half spline reads done
        if ((ng >> 1) == half) {                 // nt>>2 == ng>>1 for ni<2
#pragma unroll
            for (int mi = 0; mi < 3; ++mi) {
                int o0 = (mb2 + mi) * 16 + kgrp * 4;
                float bb0 = b2[o0], bb1 = b2[o0 + 1], bb2 = b2[o0 + 2], bb3 = b2[o0 + 3];
#pragma unroll
                for (int ni = 0; ni < 2; ++ni) {
                    int p = ((ng & 1) * 2 + ni) * 16 + lrow;   // 0..63 within half
                    f32x4 v = acc2[mi][ni];
                    pm[p * 101 + o0]     = v[0] + bb0;
                    pm[p * 101 + o0 + 1] = v[1] + bb1;
                    pm[p * 101 + o0 + 2] = v[2] + bb2;
                    pm[p * 101 + o0 + 3] = v[3] + bb3;
                }
            }
        }
        __syncthreads();
        // spline: 64 pos x 32 spline-ch = 2048 elems, 512 thr x 4 iters
#pragma unroll 4
        for (int it = 0; it < 4; ++it) {
            int idx = it * 512 + t;
            int c = idx >> 6, p = idx & 63;
            int pb = p * 101 + 3 * c;
            float u0 = pm[pb];
            float u1 = pm[pb + 1];
            float u2 = pm[pb + 2];
            size_t gpos = (size_t)(b * 64 + 32 + c) * 4096 + (size_t)(h0 + half) * 64 + p;
            float xin = x[gpos];
            float mx = fmaxf(u0, fmaxf(u1, u2));
            float e0 = __expf(u0 - mx), e1 = __expf(u1 - mx), e2 = __expf(u2 - mx);
            float s = e0 + e1 + e2;
            float inv = 1.0f / s;
            float pos01 = fminf(fmaxf((xin + 1.f) * 0.5f, 0.f), 1.f) * 3.f;
            int bin = (int)pos01; bin = bin > 2 ? 2 : bin;
            float alpha = pos01 - (float)bin;
            float eb = (bin == 0) ? e0 : ((bin == 1) ? e1 : e2);
            float cb = (bin == 0) ? 0.f : ((bin == 1) ? e0 : (e0 + e1));
            float pk = eb * inv;
            float outv = cb * inv + alpha * pk;
            outv = fminf(fmaxf(outv, 0.f), 1.f) * 2.f - 1.f;
            float lad = __logf(pk) + 1.09861228866810969f;   // + log(3)
            bool inside = (xin >= -1.f) && (xin <= 1.f);
            if (!inside) { outv = xin; lad = 0.f; }
            out[gpos] = outv;
            lad_acc += lad;
        }
    }
#pragma unroll
    for (int off = 32; off > 0; off >>= 1)
        lad_acc += __shfl_down(lad_acc, off, 64);
    if (lane == 0) red[wid] = lad_acc;
    __syncthreads();
    if (t == 0) {
        float s = 0.f;
#pragma unroll
        for (int i = 0; i < 8; ++i) s += red[i];
        atomicAdd(out + 8388608 + b, s);
    }
}

extern "C" void kernel_launch(void* const* d_in, const int* in_sizes, int n_in,
                              void* d_out, int out_size, void* d_ws, size_t ws_size,
                              hipStream_t stream) {
    const float* x   = (const float*)d_in[0];
    const float* obj = (const float*)d_in[1];
    const float* W1  = (const float*)d_in[2];
    const float* b1  = (const float*)d_in[3];
    const float* W2  = (const float*)d_in[4];
    const float* b2  = (const float*)d_in[5];
    float* out = (float*)d_out;
    char* ws = (char*)d_ws;

    unsigned short* Wt1 = (unsigned short*)ws;                   //  73,728 B
    unsigned short* Wt2 = (unsigned short*)(ws + 73728);         // 221,184 B

    hipLaunchKernelGGL(prep_w, dim3(432),  dim3(256), 0, stream, W1, W2, obj, Wt1, Wt2, out);
    hipLaunchKernelGGL(mega,   dim3(1024), dim3(512), 0, stream, x, b1, b2, Wt1, Wt2, out);
}

// Round 22
// 77.022 us; speedup vs baseline: 1.1518x; 1.1518x over previous
//
#include <hip/hip_runtime.h>

typedef __attribute__((ext_vector_type(8))) __bf16 bf16x8;
typedef __attribute__((ext_vector_type(4))) float f32x4;

__device__ __forceinline__ unsigned short f2bf(float f) {
    unsigned int u = __builtin_bit_cast(unsigned int, f);
    u = (u + 0x7FFFu + ((u >> 16) & 1u)) >> 16;
    return (unsigned short)u;
}

// ---- K0: repack weights. Wt1: [tap][o][i].
//      Wt2: fragment-major per slice s=kc*9+tap:
//      elem = s*6144 + ((o_tile*2 + khalf)*64 + kgrp*16 + lrow)*8 + j ----
__global__ void __launch_bounds__(256) prep_w(const float* __restrict__ W1,
                                              const float* __restrict__ W2,
                                              unsigned short* __restrict__ Wt1,
                                              unsigned short* __restrict__ Wt2) {
    int tid = blockIdx.x * 256 + threadIdx.x;
    if (tid < 36864) {                       // W1: [128][32][9]
        int tt = tid % 9, rem = tid / 9;
        int i = rem & 31, o = rem >> 5;
        Wt1[(tt * 128 + o) * 32 + i] = f2bf(W1[tid]);
    }
    if (tid < 110592) {                      // W2: [96][128][9] -> fragment-major
        int tt = tid % 9, rem = tid / 9;
        int i = rem & 127, o = rem >> 7;
        int kc = i >> 6, ii = i & 63;
        int khalf = ii >> 5, kgrp = (ii >> 3) & 3, j = ii & 7;
        int o_tile = o >> 4, lrow = o & 15;
        int s = kc * 9 + tt;
        Wt2[(size_t)s * 6144 +
            (size_t)(((o_tile * 2 + khalf) * 64 + kgrp * 16 + lrow) * 8 + j)] = f2bf(W2[tid]);
    }
}

// ---- K1 fused (r20, proven): identity copy + objective init + packed
//      transpose-stage + conv1 + bias + ReLU -> h bf16 channel-last ----
__global__ void __launch_bounds__(256) conv1_fused(const float* __restrict__ x,
                                                   const float* __restrict__ obj,
                                                   const float* __restrict__ b1,
                                                   const unsigned short* __restrict__ Wt1,
                                                   unsigned short* __restrict__ hbuf,
                                                   float* __restrict__ out) {
    const int LW = 40;                          // 32 ch + 8 pad
    __shared__ unsigned short sx[6 * 66 * LW];  // 31,680 B
    int wg = blockIdx.x;
    int b = wg >> 4, h0 = (wg & 15) << 2;       // TH = 4 rows
    int t = threadIdx.x;

    // -- identity half copy (f32 float4) + objective init --
#pragma unroll
    for (int j = 0; j < 8; ++j) {
        int idx = j * 256 + t;                  // 2048 float4 = 4 rows x 32 ch x 16 w4
        int c = idx >> 6, row = (idx >> 4) & 3, w4 = idx & 15;
        size_t off = (((size_t)b * 64 + c) * 64 + (h0 + row)) * 16 + w4;  // float4 units
        reinterpret_cast<float4*>(out)[off] =
            reinterpret_cast<const float4*>(x)[off];
    }
    if (wg == 0 && t < 32) out[8388608 + t] = obj[t];

    // -- stage + transpose x[b, 0:32, h0-1..h0+4, :] -> sx[row][w+1][c] bf16 --
    if (t < 48) {                               // zero halo cols 0 and 65
        int row = t >> 3, k = t & 7;
        int col = (k & 1) ? 65 : 0, c0 = (k >> 1) * 8;
        *reinterpret_cast<uint4*>(&sx[(row * 66 + col) * LW + c0]) = uint4{0, 0, 0, 0};
    }
    {
        int w = t & 63, c2 = (t >> 6) * 2;      // each thread: 2 adjacent channels
        const float* xb = x + (size_t)b * 262144;
#pragma unroll
        for (int row = 0; row < 6; ++row) {
            int gh = h0 - 1 + row;
            unsigned short* srow = &sx[(row * 66 + w + 1) * LW];
            if (gh >= 0 && gh < 64) {
                const float* xr = xb + (size_t)gh * 64;
#pragma unroll
                for (int co = 0; co < 4; ++co) {
                    int c = co * 8 + c2;
                    float f0 = xr[(size_t)c * 4096 + w];
                    float f1 = xr[(size_t)(c + 1) * 4096 + w];
                    unsigned pk = (unsigned)f2bf(f0) | ((unsigned)f2bf(f1) << 16);
                    *reinterpret_cast<unsigned*>(&srow[c]) = pk;
                }
            } else {
#pragma unroll
                for (int co = 0; co < 4; ++co) {
                    int c = co * 8 + c2;
                    *reinterpret_cast<unsigned*>(&srow[c]) = 0u;
                }
            }
        }
    }
    __syncthreads();

    int wid = t >> 6, lane = t & 63;
    int lrow = lane & 15, kgrp = lane >> 4;

    bf16x8 afr[2][9];                           // hoist weights: 2 M-tiles x 9 taps
#pragma unroll
    for (int m2 = 0; m2 < 2; ++m2) {
        int o = (wid * 2 + m2) * 16 + lrow;
#pragma unroll
        for (int tap = 0; tap < 9; ++tap)
            afr[m2][tap] = *reinterpret_cast<const bf16x8*>(
                Wt1 + (size_t)(tap * 128 + o) * 32 + kgrp * 8);
    }

    for (int nt = 0; nt < 16; ++nt) {
        int r = nt >> 2, ww = ((nt & 3) << 4) + lrow;
        f32x4 acc0 = {0.f, 0.f, 0.f, 0.f}, acc1 = {0.f, 0.f, 0.f, 0.f};
#pragma unroll
        for (int dh = 0; dh < 3; ++dh)
#pragma unroll
            for (int dw = 0; dw < 3; ++dw) {
                int tap = dh * 3 + dw;
                bf16x8 bfr = *reinterpret_cast<const bf16x8*>(
                    &sx[((r + dh) * 66 + ww + dw) * LW + kgrp * 8]);
                acc0 = __builtin_amdgcn_mfma_f32_16x16x32_bf16(afr[0][tap], bfr, acc0, 0, 0, 0);
                acc1 = __builtin_amdgcn_mfma_f32_16x16x32_bf16(afr[1][tap], bfr, acc1, 0, 0, 0);
            }
        int hh = h0 + r;
        size_t obase = (((size_t)b * 64 + hh) * 64 + ww) * 128;
#pragma unroll
        for (int m2 = 0; m2 < 2; ++m2) {
            f32x4 a = (m2 == 0) ? acc0 : acc1;
            int o0 = (wid * 2 + m2) * 16 + kgrp * 4;
            unsigned short r4[4];
#pragma unroll
            for (int j = 0; j < 4; ++j) {
                float v = a[j] + b1[o0 + j];
                r4[j] = f2bf(fmaxf(v, 0.f));
            }
            uint2 pk;
            pk.x = (unsigned)r4[0] | ((unsigned)r4[1] << 16);
            pk.y = (unsigned)r4[2] | ((unsigned)r4[3] << 16);
            *reinterpret_cast<uint2*>(hbuf + obase + o0) = pk;
        }
    }
}

// ---- K2 v17: 6M x 2N wave ownership (was 3M x 4N). Each wave computes all
//      96 out-ch for its 2 N-tiles -> act LDS reads HALVED (the ~22us
//      ds_read_b128 throughput component). Weights L2/L1-direct, padded act
//      LDS, barrier-free tap loop (all from r14 best).
__global__ void __launch_bounds__(512) conv2_spline(const unsigned short* __restrict__ hbuf,
                                                    const float* __restrict__ b2,
                                                    const unsigned short* __restrict__ Wt2,
                                                    const float* __restrict__ x,
                                                    float* __restrict__ out) {
    const int LWA = 72;                          // act: 64 ch + 8 pad
    __shared__ __align__(16) unsigned short sa[6 * 66 * LWA];  // 57,024 B
    __shared__ float red[8];
    float* pm = reinterpret_cast<float*>(sa);    // params alias [128][101] f32 = 51,712 B

    int raw = blockIdx.x;                        // 512 blocks
    int wg = (raw & 7) * 64 + (raw >> 3);        // XCD-contiguous swizzle (bijective)
    int b = wg >> 4, h0 = (wg & 15) << 2;        // TH = 4 rows
    int t = threadIdx.x;
    int wid = t >> 6, lane = t & 63;
    int lrow = lane & 15, kgrp = lane >> 4;

    f32x4 acc[6][2];
#pragma unroll
    for (int i = 0; i < 6; ++i)
#pragma unroll
        for (int j = 0; j < 2; ++j) acc[i][j] = f32x4{0.f, 0.f, 0.f, 0.f};

    // per-lane weight fragment base (fragment-major layout)
    const unsigned short* wfb = Wt2 + (size_t)lane * 8;

    for (int kc2 = 0; kc2 < 2; ++kc2) {          // two 64-channel K chunks
        if (kc2) __syncthreads();                // all tap reads of sa done
        // stage act: rows h0-1..h0+4, 64 w, 64 ch (3072 uint4)
#pragma unroll
        for (int j = 0; j < 6; ++j) {
            int idx = j * 512 + t;
            int row = idx >> 9, rem = idx & 511;
            int w = rem >> 3, c0 = (rem & 7) * 8;
            int gh = h0 - 1 + row;
            uint4 v = uint4{0, 0, 0, 0};
            if (gh >= 0 && gh < 64)
                v = *reinterpret_cast<const uint4*>(
                    hbuf + (((size_t)b * 64 + gh) * 64 + w) * 128 + kc2 * 64 + c0);
            *reinterpret_cast<uint4*>(&sa[(row * 66 + (w + 1)) * LWA + c0]) = v;
        }
        if (t < 96) {                            // zero halo cols 0 and 65
            int row = t >> 4, k = t & 15;
            int col = (k & 1) ? 65 : 0, c0 = (k >> 1) * 8;
            *reinterpret_cast<uint4*>(&sa[(row * 66 + col) * LWA + c0]) = uint4{0, 0, 0, 0};
        }
        __syncthreads();                         // act visible

#pragma unroll
        for (int tap = 0; tap < 9; ++tap) {
            int s = kc2 * 9 + tap;
            const unsigned short* wsl = wfb + (size_t)s * 6144;
            int dh = tap / 3, dw = tap % 3;
            bf16x8 wfr[6][2];
#pragma unroll
            for (int mi = 0; mi < 6; ++mi) {
                wfr[mi][0] = *reinterpret_cast<const bf16x8*>(wsl + (size_t)(mi * 2 + 0) * 512);
                wfr[mi][1] = *reinterpret_cast<const bf16x8*>(wsl + (size_t)(mi * 2 + 1) * 512);
            }
#pragma unroll
            for (int ni = 0; ni < 2; ++ni) {
                int nt = wid * 2 + ni;           // 0..15
                int rr = nt >> 2, wcol = (nt & 3) * 16 + lrow;
                int base = ((rr + dh) * 66 + wcol + dw) * LWA;
                bf16x8 a0 = *reinterpret_cast<const bf16x8*>(&sa[base + kgrp * 8]);
                bf16x8 a1 = *reinterpret_cast<const bf16x8*>(&sa[base + 32 + kgrp * 8]);
#pragma unroll
                for (int mi = 0; mi < 6; ++mi) {
                    acc[mi][ni] = __builtin_amdgcn_mfma_f32_16x16x32_bf16(wfr[mi][0], a0, acc[mi][ni], 0, 0, 0);
                    acc[mi][ni] = __builtin_amdgcn_mfma_f32_16x16x32_bf16(wfr[mi][1], a1, acc[mi][ni], 0, 0, 0);
                }
            }
        }
    }

    // ---- epilogue: two 128-position halves (params f32 aliased over sa) ----
    // wave wid owns row = wid>>1 (global pos row 0..3), half = wid>>2.
    float lad_acc = 0.f;
    for (int half = 0; half < 2; ++half) {
        __syncthreads();                         // acc done / prev-half spline reads done
        if ((wid >> 2) == half) {
#pragma unroll
            for (int mi = 0; mi < 6; ++mi) {
                int o0 = mi * 16 + kgrp * 4;
                float bb0 = b2[o0], bb1 = b2[o0 + 1], bb2 = b2[o0 + 2], bb3 = b2[o0 + 3];
#pragma unroll
                for (int ni = 0; ni < 2; ++ni) {
                    int nt = wid * 2 + ni;
                    int p = ((nt >> 2) & 1) * 64 + (nt & 3) * 16 + lrow;  // 0..127 in half
                    f32x4 v = acc[mi][ni];
                    pm[p * 101 + o0]     = v[0] + bb0;
                    pm[p * 101 + o0 + 1] = v[1] + bb1;
                    pm[p * 101 + o0 + 2] = v[2] + bb2;
                    pm[p * 101 + o0 + 3] = v[3] + bb3;
                }
            }
        }
        __syncthreads();
        // spline: 128 pos x 32 spline-ch = 4096 elems, 512 thr x 8 iters
#pragma unroll 4
        for (int it = 0; it < 8; ++it) {
            int idx = it * 512 + t;
            int c = idx >> 7, p = idx & 127;
            int pos = half * 128 + p;
            int pb = p * 101 + 3 * c;
            float u0 = pm[pb];
            float u1 = pm[pb + 1];
            float u2 = pm[pb + 2];
            size_t gpos = (size_t)(b * 64 + 32 + c) * 4096 + (size_t)(h0 + (pos >> 6)) * 64 + (pos & 63);
            float xin = x[gpos];
            float mx = fmaxf(u0, fmaxf(u1, u2));
            float e0 = __expf(u0 - mx), e1 = __expf(u1 - mx), e2 = __expf(u2 - mx);
            float s = e0 + e1 + e2;
            float inv = 1.0f / s;
            float pos01 = fminf(fmaxf((xin + 1.f) * 0.5f, 0.f), 1.f) * 3.f;
            int bin = (int)pos01; bin = bin > 2 ? 2 : bin;
            float alpha = pos01 - (float)bin;
            float eb = (bin == 0) ? e0 : ((bin == 1) ? e1 : e2);
            float cb = (bin == 0) ? 0.f : ((bin == 1) ? e0 : (e0 + e1));
            float pk = eb * inv;
            float outv = cb * inv + alpha * pk;
            outv = fminf(fmaxf(outv, 0.f), 1.f) * 2.f - 1.f;
            float lad = __logf(pk) + 1.09861228866810969f;   // + log(3)
            bool inside = (xin >= -1.f) && (xin <= 1.f);
            if (!inside) { outv = xin; lad = 0.f; }
            out[gpos] = outv;
            lad_acc += lad;
        }
    }
#pragma unroll
    for (int off = 32; off > 0; off >>= 1)
        lad_acc += __shfl_down(lad_acc, off, 64);
    if (lane == 0) red[wid] = lad_acc;
    __syncthreads();
    if (t == 0) {
        float s = 0.f;
#pragma unroll
        for (int i = 0; i < 8; ++i) s += red[i];
        atomicAdd(out + 8388608 + b, s);
    }
}

extern "C" void kernel_launch(void* const* d_in, const int* in_sizes, int n_in,
                              void* d_out, int out_size, void* d_ws, size_t ws_size,
                              hipStream_t stream) {
    const float* x   = (const float*)d_in[0];
    const float* obj = (const float*)d_in[1];
    const float* W1  = (const float*)d_in[2];
    const float* b1  = (const float*)d_in[3];
    const float* W2  = (const float*)d_in[4];
    const float* b2  = (const float*)d_in[5];
    float* out = (float*)d_out;
    char* ws = (char*)d_ws;

    unsigned short* hbuf = (unsigned short*)ws;                  // 33,554,432 B
    unsigned short* Wt1  = (unsigned short*)(ws + 33554432);     //     73,728 B
    unsigned short* Wt2  = (unsigned short*)(ws + 33554432 + 73728); // 221,184 B

    hipLaunchKernelGGL(prep_w,       dim3(432), dim3(256), 0, stream, W1, W2, Wt1, Wt2);
    hipLaunchKernelGGL(conv1_fused,  dim3(512), dim3(256), 0, stream, x, obj, b1, Wt1, hbuf, out);
    hipLaunchKernelGGL(conv2_spline, dim3(512), dim3(512), 0, stream, hbuf, b2, Wt2, x, out);
}

// Round 23
// 71.161 us; speedup vs baseline: 1.2467x; 1.0824x over previous
//
#include <hip/hip_runtime.h>

typedef __attribute__((ext_vector_type(8))) __bf16 bf16x8;
typedef __attribute__((ext_vector_type(4))) float f32x4;

__device__ __forceinline__ unsigned short f2bf(float f) {
    unsigned int u = __builtin_bit_cast(unsigned int, f);
    u = (u + 0x7FFFu + ((u >> 16) & 1u)) >> 16;
    return (unsigned short)u;
}

// ---- K0: repack weights. Wt1: [tap][o][i].
//      Wt2: fragment-major per slice s=kc*9+tap:
//      elem = s*6144 + ((o_tile*2 + khalf)*64 + kgrp*16 + lrow)*8 + j ----
__global__ void __launch_bounds__(256) prep_w(const float* __restrict__ W1,
                                              const float* __restrict__ W2,
                                              unsigned short* __restrict__ Wt1,
                                              unsigned short* __restrict__ Wt2) {
    int tid = blockIdx.x * 256 + threadIdx.x;
    if (tid < 36864) {                       // W1: [128][32][9]
        int tt = tid % 9, rem = tid / 9;
        int i = rem & 31, o = rem >> 5;
        Wt1[(tt * 128 + o) * 32 + i] = f2bf(W1[tid]);
    }
    if (tid < 110592) {                      // W2: [96][128][9] -> fragment-major
        int tt = tid % 9, rem = tid / 9;
        int i = rem & 127, o = rem >> 7;
        int kc = i >> 6, ii = i & 63;
        int khalf = ii >> 5, kgrp = (ii >> 3) & 3, j = ii & 7;
        int o_tile = o >> 4, lrow = o & 15;
        int s = kc * 9 + tt;
        Wt2[(size_t)s * 6144 +
            (size_t)(((o_tile * 2 + khalf) * 64 + kgrp * 16 + lrow) * 8 + j)] = f2bf(W2[tid]);
    }
}

// ---- K1 fused (r20, proven): identity copy + objective init + packed
//      transpose-stage + conv1 + bias + ReLU -> h bf16 channel-last ----
__global__ void __launch_bounds__(256) conv1_fused(const float* __restrict__ x,
                                                   const float* __restrict__ obj,
                                                   const float* __restrict__ b1,
                                                   const unsigned short* __restrict__ Wt1,
                                                   unsigned short* __restrict__ hbuf,
                                                   float* __restrict__ out) {
    const int LW = 40;                          // 32 ch + 8 pad
    __shared__ unsigned short sx[6 * 66 * LW];  // 31,680 B
    int wg = blockIdx.x;
    int b = wg >> 4, h0 = (wg & 15) << 2;       // TH = 4 rows
    int t = threadIdx.x;

    // -- identity half copy (f32 float4) + objective init --
#pragma unroll
    for (int j = 0; j < 8; ++j) {
        int idx = j * 256 + t;                  // 2048 float4 = 4 rows x 32 ch x 16 w4
        int c = idx >> 6, row = (idx >> 4) & 3, w4 = idx & 15;
        size_t off = (((size_t)b * 64 + c) * 64 + (h0 + row)) * 16 + w4;  // float4 units
        reinterpret_cast<float4*>(out)[off] =
            reinterpret_cast<const float4*>(x)[off];
    }
    if (wg == 0 && t < 32) out[8388608 + t] = obj[t];

    // -- stage + transpose x[b, 0:32, h0-1..h0+4, :] -> sx[row][w+1][c] bf16 --
    if (t < 48) {                               // zero halo cols 0 and 65
        int row = t >> 3, k = t & 7;
        int col = (k & 1) ? 65 : 0, c0 = (k >> 1) * 8;
        *reinterpret_cast<uint4*>(&sx[(row * 66 + col) * LW + c0]) = uint4{0, 0, 0, 0};
    }
    {
        int w = t & 63, c2 = (t >> 6) * 2;      // each thread: 2 adjacent channels
        const float* xb = x + (size_t)b * 262144;
#pragma unroll
        for (int row = 0; row < 6; ++row) {
            int gh = h0 - 1 + row;
            unsigned short* srow = &sx[(row * 66 + w + 1) * LW];
            if (gh >= 0 && gh < 64) {
                const float* xr = xb + (size_t)gh * 64;
#pragma unroll
                for (int co = 0; co < 4; ++co) {
                    int c = co * 8 + c2;
                    float f0 = xr[(size_t)c * 4096 + w];
                    float f1 = xr[(size_t)(c + 1) * 4096 + w];
                    unsigned pk = (unsigned)f2bf(f0) | ((unsigned)f2bf(f1) << 16);
                    *reinterpret_cast<unsigned*>(&srow[c]) = pk;
                }
            } else {
#pragma unroll
                for (int co = 0; co < 4; ++co) {
                    int c = co * 8 + c2;
                    *reinterpret_cast<unsigned*>(&srow[c]) = 0u;
                }
            }
        }
    }
    __syncthreads();

    int wid = t >> 6, lane = t & 63;
    int lrow = lane & 15, kgrp = lane >> 4;

    bf16x8 afr[2][9];                           // hoist weights: 2 M-tiles x 9 taps
#pragma unroll
    for (int m2 = 0; m2 < 2; ++m2) {
        int o = (wid * 2 + m2) * 16 + lrow;
#pragma unroll
        for (int tap = 0; tap < 9; ++tap)
            afr[m2][tap] = *reinterpret_cast<const bf16x8*>(
                Wt1 + (size_t)(tap * 128 + o) * 32 + kgrp * 8);
    }

    for (int nt = 0; nt < 16; ++nt) {
        int r = nt >> 2, ww = ((nt & 3) << 4) + lrow;
        f32x4 acc0 = {0.f, 0.f, 0.f, 0.f}, acc1 = {0.f, 0.f, 0.f, 0.f};
#pragma unroll
        for (int dh = 0; dh < 3; ++dh)
#pragma unroll
            for (int dw = 0; dw < 3; ++dw) {
                int tap = dh * 3 + dw;
                bf16x8 bfr = *reinterpret_cast<const bf16x8*>(
                    &sx[((r + dh) * 66 + ww + dw) * LW + kgrp * 8]);
                acc0 = __builtin_amdgcn_mfma_f32_16x16x32_bf16(afr[0][tap], bfr, acc0, 0, 0, 0);
                acc1 = __builtin_amdgcn_mfma_f32_16x16x32_bf16(afr[1][tap], bfr, acc1, 0, 0, 0);
            }
        int hh = h0 + r;
        size_t obase = (((size_t)b * 64 + hh) * 64 + ww) * 128;
#pragma unroll
        for (int m2 = 0; m2 < 2; ++m2) {
            f32x4 a = (m2 == 0) ? acc0 : acc1;
            int o0 = (wid * 2 + m2) * 16 + kgrp * 4;
            unsigned short r4[4];
#pragma unroll
            for (int j = 0; j < 4; ++j) {
                float v = a[j] + b1[o0 + j];
                r4[j] = f2bf(fmaxf(v, 0.f));
            }
            uint2 pk;
            pk.x = (unsigned)r4[0] | ((unsigned)r4[1] << 16);
            pk.y = (unsigned)r4[2] | ((unsigned)r4[3] << 16);
            *reinterpret_cast<uint2*>(hbuf + obase + o0) = pk;
        }
    }
}

// ---- K2 v18: r14's v13 (best, 47.1us) + s_setprio(1) around the tap MFMA
//      cluster (T5: barrier-free loop -> waves phase-drift -> scheduler can
//      favor MFMA-issuing waves). Everything else byte-identical to r14.
__global__ void __launch_bounds__(512) conv2_spline(const unsigned short* __restrict__ hbuf,
                                                    const float* __restrict__ b2,
                                                    const unsigned short* __restrict__ Wt2,
                                                    const float* __restrict__ x,
                                                    float* __restrict__ out) {
    const int LWA = 72;                          // act: 64 ch + 8 pad
    __shared__ __align__(16) unsigned short sa[6 * 66 * LWA];  // 57,024 B
    __shared__ float red[8];
    float* pm = reinterpret_cast<float*>(sa);    // params alias [128][101] f32 = 51,712 B

    int raw = blockIdx.x;                        // 512 blocks
    int wg = (raw & 7) * 64 + (raw >> 3);        // XCD-contiguous swizzle (bijective)
    int b = wg >> 4, h0 = (wg & 15) << 2;        // TH = 4 rows
    int t = threadIdx.x;
    int wid = t >> 6, lane = t & 63;
    int lrow = lane & 15, kgrp = lane >> 4;
    int mgrp = wid >> 2, ngrp = wid & 3;         // 2 Mgrp x 4 Ngrp
    int mb = mgrp * 3;                           // 3 M-tiles (48 ch) per wave

    f32x4 acc[3][4];
#pragma unroll
    for (int i = 0; i < 3; ++i)
#pragma unroll
        for (int j = 0; j < 4; ++j) acc[i][j] = f32x4{0.f, 0.f, 0.f, 0.f};

    // per-lane weight fragment base (fragment-major layout)
    const unsigned short* wfb = Wt2 + (size_t)lane * 8;

    for (int kc2 = 0; kc2 < 2; ++kc2) {          // two 64-channel K chunks
        if (kc2) __syncthreads();                // all tap reads of sa done
        // stage act: rows h0-1..h0+4, 64 w, 64 ch (3072 uint4)
#pragma unroll
        for (int j = 0; j < 6; ++j) {
            int idx = j * 512 + t;
            int row = idx >> 9, rem = idx & 511;
            int w = rem >> 3, c0 = (rem & 7) * 8;
            int gh = h0 - 1 + row;
            uint4 v = uint4{0, 0, 0, 0};
            if (gh >= 0 && gh < 64)
                v = *reinterpret_cast<const uint4*>(
                    hbuf + (((size_t)b * 64 + gh) * 64 + w) * 128 + kc2 * 64 + c0);
            *reinterpret_cast<uint4*>(&sa[(row * 66 + (w + 1)) * LWA + c0]) = v;
        }
        if (t < 96) {                            // zero halo cols 0 and 65
            int row = t >> 4, k = t & 15;
            int col = (k & 1) ? 65 : 0, c0 = (k >> 1) * 8;
            *reinterpret_cast<uint4*>(&sa[(row * 66 + col) * LWA + c0]) = uint4{0, 0, 0, 0};
        }
        __syncthreads();                         // act visible

#pragma unroll
        for (int tap = 0; tap < 9; ++tap) {
            int s = kc2 * 9 + tap;
            const unsigned short* wsl = wfb + (size_t)s * 6144;
            int dh = tap / 3, dw = tap % 3;
            bf16x8 wfr[3][2];
#pragma unroll
            for (int mi = 0; mi < 3; ++mi) {
                int ot = mb + mi;
                wfr[mi][0] = *reinterpret_cast<const bf16x8*>(wsl + (size_t)(ot * 2 + 0) * 512);
                wfr[mi][1] = *reinterpret_cast<const bf16x8*>(wsl + (size_t)(ot * 2 + 1) * 512);
            }
            __builtin_amdgcn_s_setprio(1);       // favor this wave through the MFMA cluster
#pragma unroll
            for (int ni = 0; ni < 4; ++ni) {
                int nt = ngrp * 4 + ni;
                int rr = nt >> 2, wcol = (nt & 3) * 16 + lrow;
                int base = ((rr + dh) * 66 + wcol + dw) * LWA;
                bf16x8 a0 = *reinterpret_cast<const bf16x8*>(&sa[base + kgrp * 8]);
                bf16x8 a1 = *reinterpret_cast<const bf16x8*>(&sa[base + 32 + kgrp * 8]);
#pragma unroll
                for (int mi = 0; mi < 3; ++mi) {
                    acc[mi][ni] = __builtin_amdgcn_mfma_f32_16x16x32_bf16(wfr[mi][0], a0, acc[mi][ni], 0, 0, 0);
                    acc[mi][ni] = __builtin_amdgcn_mfma_f32_16x16x32_bf16(wfr[mi][1], a1, acc[mi][ni], 0, 0, 0);
                }
            }
            __builtin_amdgcn_s_setprio(0);
        }
    }

    // ---- epilogue: two 128-position halves (params f32 aliased over sa) ----
    float lad_acc = 0.f;
    for (int half = 0; half < 2; ++half) {
        __syncthreads();                         // acc done / prev-half spline reads done
        if ((ngrp >> 1) == half) {               // ngrp {0,1}->half0, {2,3}->half1
#pragma unroll
            for (int mi = 0; mi < 3; ++mi) {
                int o0 = (mb + mi) * 16 + kgrp * 4;
                float bb0 = b2[o0], bb1 = b2[o0 + 1], bb2 = b2[o0 + 2], bb3 = b2[o0 + 3];
#pragma unroll
                for (int ni = 0; ni < 4; ++ni) {
                    int p = (ngrp & 1) * 64 + ni * 16 + lrow;   // 0..127 within half
                    f32x4 v = acc[mi][ni];
                    pm[p * 101 + o0]     = v[0] + bb0;
                    pm[p * 101 + o0 + 1] = v[1] + bb1;
                    pm[p * 101 + o0 + 2] = v[2] + bb2;
                    pm[p * 101 + o0 + 3] = v[3] + bb3;
                }
            }
        }
        __syncthreads();
        // spline: 128 pos x 32 spline-ch = 4096 elems, 512 thr x 8 iters
#pragma unroll 4
        for (int it = 0; it < 8; ++it) {
            int idx = it * 512 + t;
            int c = idx >> 7, p = idx & 127;
            int pos = half * 128 + p;
            int pb = p * 101 + 3 * c;
            float u0 = pm[pb];
            float u1 = pm[pb + 1];
            float u2 = pm[pb + 2];
            size_t gpos = (size_t)(b * 64 + 32 + c) * 4096 + (size_t)(h0 + (pos >> 6)) * 64 + (pos & 63);
            float xin = x[gpos];
            float mx = fmaxf(u0, fmaxf(u1, u2));
            float e0 = __expf(u0 - mx), e1 = __expf(u1 - mx), e2 = __expf(u2 - mx);
            float s = e0 + e1 + e2;
            float inv = 1.0f / s;
            float pos01 = fminf(fmaxf((xin + 1.f) * 0.5f, 0.f), 1.f) * 3.f;
            int bin = (int)pos01; bin = bin > 2 ? 2 : bin;
            float alpha = pos01 - (float)bin;
            float eb = (bin == 0) ? e0 : ((bin == 1) ? e1 : e2);
            float cb = (bin == 0) ? 0.f : ((bin == 1) ? e0 : (e0 + e1));
            float pk = eb * inv;
            float outv = cb * inv + alpha * pk;
            outv = fminf(fmaxf(outv, 0.f), 1.f) * 2.f - 1.f;
            float lad = __logf(pk) + 1.09861228866810969f;   // + log(3)
            bool inside = (xin >= -1.f) && (xin <= 1.f);
            if (!inside) { outv = xin; lad = 0.f; }
            out[gpos] = outv;
            lad_acc += lad;
        }
    }
#pragma unroll
    for (int off = 32; off > 0; off >>= 1)
        lad_acc += __shfl_down(lad_acc, off, 64);
    if (lane == 0) red[wid] = lad_acc;
    __syncthreads();
    if (t == 0) {
        float s = 0.f;
#pragma unroll
        for (int i = 0; i < 8; ++i) s += red[i];
        atomicAdd(out + 8388608 + b, s);
    }
}

extern "C" void kernel_launch(void* const* d_in, const int* in_sizes, int n_in,
                              void* d_out, int out_size, void* d_ws, size_t ws_size,
                              hipStream_t stream) {
    const float* x   = (const float*)d_in[0];
    const float* obj = (const float*)d_in[1];
    const float* W1  = (const float*)d_in[2];
    const float* b1  = (const float*)d_in[3];
    const float* W2  = (const float*)d_in[4];
    const float* b2  = (const float*)d_in[5];
    float* out = (float*)d_out;
    char* ws = (char*)d_ws;

    unsigned short* hbuf = (unsigned short*)ws;                  // 33,554,432 B
    unsigned short* Wt1  = (unsigned short*)(ws + 33554432);     //     73,728 B
    unsigned short* Wt2  = (unsigned short*)(ws + 33554432 + 73728); // 221,184 B

    hipLaunchKernelGGL(prep_w,       dim3(432), dim3(256), 0, stream, W1, W2, Wt1, Wt2);
    hipLaunchKernelGGL(conv1_fused,  dim3(512), dim3(256), 0, stream, x, obj, b1, Wt1, hbuf, out);
    hipLaunchKernelGGL(conv2_spline, dim3(512), dim3(512), 0, stream, hbuf, b2, Wt2, x, out);
}